// Round 1
// baseline (1425.229 us; speedup 1.0000x reference)
//
#include <hip/hip_runtime.h>

#define NLV 16
#define TBL (1u << 19)
#define TMASK (TBL - 1u)
#define P1 2654435761u
#define P2 805459861u

__global__ __launch_bounds__(256) void ngp_encode_kernel(
    const float* __restrict__ xyz,
    const float* __restrict__ tables,
    const int* __restrict__ resolutions,
    float* __restrict__ out,
    int n)
{
    int p = blockIdx.x * blockDim.x + threadIdx.x;
    if (p >= n) return;

    float x = xyz[(size_t)p * 3 + 0];
    float y = xyz[(size_t)p * 3 + 1];
    float z = xyz[(size_t)p * 3 + 2];
    // u = xyz / SIZE + 0.5, SIZE = 2.0 (exact: *0.5)
    float ux = x * 0.5f + 0.5f;
    float uy = y * 0.5f + 0.5f;
    float uz = z * 0.5f + 0.5f;

    float acc[NLV * 2];

#pragma unroll
    for (int L = 0; L < NLV; ++L) {
        float res = (float)resolutions[L];
        float px = ux * res, py = uy * res, pz = uz * res;
        float fx = floorf(px), fy = floorf(py), fz = floorf(pz);
        float wx = px - fx, wy = py - fy, wz = pz - fz;
        unsigned cx = (unsigned)fx, cy = (unsigned)fy, cz = (unsigned)fz;

        // incremental hash components: (c+1)*P == c*P + P (mod 2^32)
        unsigned hx0 = cx;             // * 1
        unsigned hx1 = cx + 1u;
        unsigned hy0 = cy * P1;
        unsigned hy1 = hy0 + P1;
        unsigned hz0 = cz * P2;
        unsigned hz1 = hz0 + P2;

        const float2* __restrict__ tab =
            (const float2*)(tables + (size_t)L * TBL * 2u);

        float vx0 = 1.0f - wx, vy0 = 1.0f - wy, vz0 = 1.0f - wz;

        float a0 = 0.0f, a1 = 0.0f;
#pragma unroll
        for (int c = 0; c < 8; ++c) {
            unsigned h = ((c & 1) ? hx1 : hx0) ^
                         ((c & 2) ? hy1 : hy0) ^
                         ((c & 4) ? hz1 : hz0);
            float2 f = tab[h & TMASK];
            float w = ((c & 1) ? wx : vx0) *
                      ((c & 2) ? wy : vy0) *
                      ((c & 4) ? wz : vz0);
            a0 += f.x * w;
            a1 += f.y * w;
        }
        acc[L * 2 + 0] = a0;
        acc[L * 2 + 1] = a1;
    }

    float4* o = (float4*)(out + (size_t)p * (NLV * 2));
#pragma unroll
    for (int i = 0; i < 8; ++i)
        o[i] = make_float4(acc[i * 4 + 0], acc[i * 4 + 1],
                           acc[i * 4 + 2], acc[i * 4 + 3]);
}

extern "C" void kernel_launch(void* const* d_in, const int* in_sizes, int n_in,
                              void* d_out, int out_size, void* d_ws, size_t ws_size,
                              hipStream_t stream) {
    const float* xyz = (const float*)d_in[0];
    const float* tables = (const float*)d_in[1];
    const int* resolutions = (const int*)d_in[2];
    float* out = (float*)d_out;

    int n = in_sizes[0] / 3;
    const int block = 256;
    int grid = (n + block - 1) / block;
    hipLaunchKernelGGL(ngp_encode_kernel, dim3(grid), dim3(block), 0, stream,
                       xyz, tables, resolutions, out, n);
}

// Round 2
// 1035.634 us; speedup vs baseline: 1.3762x; 1.3762x over previous
//
#include <hip/hip_runtime.h>

#define NLV 16
#define TBL (1u << 19)
#define TMASK (TBL - 1u)
#define P1 2654435761u
#define P2 805459861u

// ---------------------------------------------------------------------------
// Pass 1: level-major gather for levels [K0, 16).
// Grid ordered level-major so all concurrently-resident blocks share one
// <=4MB table -> table stays L2-resident per XCD.
// Each block: 256 threads, 512 points (2 per thread for MLP: 16 loads in
// flight per thread before any consume).
// Writes ws laid out [L-K0][n] float2, fully coalesced.
// ---------------------------------------------------------------------------
__global__ __launch_bounds__(256) void ngp_gather_levels(
    const float* __restrict__ xyz,
    const float* __restrict__ tables,
    const int* __restrict__ resolutions,
    float2* __restrict__ ws,
    int n, int nbPerLevel, int k0)
{
    int L = blockIdx.x / nbPerLevel + k0;
    int chunk = blockIdx.x % nbPerLevel;
    int p0 = chunk * 512 + (int)threadIdx.x;

    float res = (float)resolutions[L];
    const float2* __restrict__ tab = (const float2*)tables + (size_t)L * TBL;
    float2* __restrict__ wl = ws + (size_t)(L - k0) * n;

    unsigned idx[2][8];
    float wgt[2][8];
    bool valid[2];

#pragma unroll
    for (int q = 0; q < 2; ++q) {
        int p = p0 + q * 256;
        valid[q] = (p < n);
        int pp = valid[q] ? p : 0;
        float x = xyz[(size_t)pp * 3 + 0];
        float y = xyz[(size_t)pp * 3 + 1];
        float z = xyz[(size_t)pp * 3 + 2];
        float ux = x * 0.5f + 0.5f;
        float uy = y * 0.5f + 0.5f;
        float uz = z * 0.5f + 0.5f;
        float px = ux * res, py = uy * res, pz = uz * res;
        float fx = floorf(px), fy = floorf(py), fz = floorf(pz);
        float wx = px - fx, wy = py - fy, wz = pz - fz;
        unsigned cx = (unsigned)fx, cy = (unsigned)fy, cz = (unsigned)fz;
        unsigned hx0 = cx, hx1 = cx + 1u;           // prime_x == 1
        unsigned hy0 = cy * P1, hy1 = hy0 + P1;     // (c+1)*P == c*P + P
        unsigned hz0 = cz * P2, hz1 = hz0 + P2;
        float vx = 1.0f - wx, vy = 1.0f - wy, vz = 1.0f - wz;
#pragma unroll
        for (int c = 0; c < 8; ++c) {
            idx[q][c] = ((((c & 1) ? hx1 : hx0) ^
                          ((c & 2) ? hy1 : hy0) ^
                          ((c & 4) ? hz1 : hz0)) & TMASK);
            wgt[q][c] = ((c & 1) ? wx : vx) *
                        ((c & 2) ? wy : vy) *
                        ((c & 4) ? wz : vz);
        }
    }

    // issue all 16 gathers before consuming any (MLP)
    float2 f[2][8];
#pragma unroll
    for (int q = 0; q < 2; ++q)
#pragma unroll
        for (int c = 0; c < 8; ++c)
            f[q][c] = tab[idx[q][c]];

#pragma unroll
    for (int q = 0; q < 2; ++q) {
        float a0 = 0.0f, a1 = 0.0f;
#pragma unroll
        for (int c = 0; c < 8; ++c) {
            a0 += f[q][c].x * wgt[q][c];
            a1 += f[q][c].y * wgt[q][c];
        }
        int p = p0 + q * 256;
        if (valid[q]) wl[p] = make_float2(a0, a1);
    }
}

// ---------------------------------------------------------------------------
// Pass 2: per-point finalize. Computes dense levels [0, K0) directly
// (tiny line-footprint, L2-resident on all XCDs), merges levels [K0,16)
// from ws (14 coalesced streams), writes [N][32] row as 8 x float4.
// K0 is a compile-time template parameter so acc[] stays in registers.
// ---------------------------------------------------------------------------
template <int K0>
__global__ __launch_bounds__(256) void ngp_finalize(
    const float* __restrict__ xyz,
    const float* __restrict__ tables,
    const int* __restrict__ resolutions,
    const float2* __restrict__ ws,
    float* __restrict__ out, int n)
{
    int p = blockIdx.x * 256 + threadIdx.x;
    if (p >= n) return;

    float x = xyz[(size_t)p * 3 + 0];
    float y = xyz[(size_t)p * 3 + 1];
    float z = xyz[(size_t)p * 3 + 2];
    float ux = x * 0.5f + 0.5f;
    float uy = y * 0.5f + 0.5f;
    float uz = z * 0.5f + 0.5f;

    float acc[NLV * 2];

    // merged hashed levels from ws (coalesced streaming reads) — issue first
    float2 m[NLV - K0];
#pragma unroll
    for (int L = K0; L < NLV; ++L)
        m[L - K0] = ws[(size_t)(L - K0) * n + p];

    // dense low levels computed in-place
#pragma unroll
    for (int L = 0; L < K0; ++L) {
        float res = (float)resolutions[L];
        float px = ux * res, py = uy * res, pz = uz * res;
        float fx = floorf(px), fy = floorf(py), fz = floorf(pz);
        float wx = px - fx, wy = py - fy, wz = pz - fz;
        unsigned cx = (unsigned)fx, cy = (unsigned)fy, cz = (unsigned)fz;
        unsigned hx0 = cx, hx1 = cx + 1u;
        unsigned hy0 = cy * P1, hy1 = hy0 + P1;
        unsigned hz0 = cz * P2, hz1 = hz0 + P2;
        const float2* __restrict__ tab = (const float2*)tables + (size_t)L * TBL;
        float vx = 1.0f - wx, vy = 1.0f - wy, vz = 1.0f - wz;
        float a0 = 0.0f, a1 = 0.0f;
#pragma unroll
        for (int c = 0; c < 8; ++c) {
            unsigned h = ((c & 1) ? hx1 : hx0) ^
                         ((c & 2) ? hy1 : hy0) ^
                         ((c & 4) ? hz1 : hz0);
            float2 f = tab[h & TMASK];
            float w = ((c & 1) ? wx : vx) *
                      ((c & 2) ? wy : vy) *
                      ((c & 4) ? wz : vz);
            a0 += f.x * w;
            a1 += f.y * w;
        }
        acc[L * 2 + 0] = a0;
        acc[L * 2 + 1] = a1;
    }

#pragma unroll
    for (int L = K0; L < NLV; ++L) {
        acc[L * 2 + 0] = m[L - K0].x;
        acc[L * 2 + 1] = m[L - K0].y;
    }

    float4* o = (float4*)(out + (size_t)p * (NLV * 2));
#pragma unroll
    for (int i = 0; i < 8; ++i)
        o[i] = make_float4(acc[i * 4 + 0], acc[i * 4 + 1],
                           acc[i * 4 + 2], acc[i * 4 + 3]);
}

// ---------------------------------------------------------------------------
// Fallback: original single-pass point-major kernel (used if ws too small).
// ---------------------------------------------------------------------------
__global__ __launch_bounds__(256) void ngp_encode_kernel(
    const float* __restrict__ xyz,
    const float* __restrict__ tables,
    const int* __restrict__ resolutions,
    float* __restrict__ out,
    int n)
{
    int p = blockIdx.x * blockDim.x + threadIdx.x;
    if (p >= n) return;

    float x = xyz[(size_t)p * 3 + 0];
    float y = xyz[(size_t)p * 3 + 1];
    float z = xyz[(size_t)p * 3 + 2];
    float ux = x * 0.5f + 0.5f;
    float uy = y * 0.5f + 0.5f;
    float uz = z * 0.5f + 0.5f;

    float acc[NLV * 2];

#pragma unroll
    for (int L = 0; L < NLV; ++L) {
        float res = (float)resolutions[L];
        float px = ux * res, py = uy * res, pz = uz * res;
        float fx = floorf(px), fy = floorf(py), fz = floorf(pz);
        float wx = px - fx, wy = py - fy, wz = pz - fz;
        unsigned cx = (unsigned)fx, cy = (unsigned)fy, cz = (unsigned)fz;
        unsigned hx0 = cx, hx1 = cx + 1u;
        unsigned hy0 = cy * P1, hy1 = hy0 + P1;
        unsigned hz0 = cz * P2, hz1 = hz0 + P2;
        const float2* __restrict__ tab = (const float2*)tables + (size_t)L * TBL;
        float vx = 1.0f - wx, vy = 1.0f - wy, vz = 1.0f - wz;
        float a0 = 0.0f, a1 = 0.0f;
#pragma unroll
        for (int c = 0; c < 8; ++c) {
            unsigned h = ((c & 1) ? hx1 : hx0) ^
                         ((c & 2) ? hy1 : hy0) ^
                         ((c & 4) ? hz1 : hz0);
            float2 f = tab[h & TMASK];
            float w = ((c & 1) ? wx : vx) *
                      ((c & 2) ? wy : vy) *
                      ((c & 4) ? wz : vz);
            a0 += f.x * w;
            a1 += f.y * w;
        }
        acc[L * 2 + 0] = a0;
        acc[L * 2 + 1] = a1;
    }

    float4* o = (float4*)(out + (size_t)p * (NLV * 2));
#pragma unroll
    for (int i = 0; i < 8; ++i)
        o[i] = make_float4(acc[i * 4 + 0], acc[i * 4 + 1],
                           acc[i * 4 + 2], acc[i * 4 + 3]);
}

extern "C" void kernel_launch(void* const* d_in, const int* in_sizes, int n_in,
                              void* d_out, int out_size, void* d_ws, size_t ws_size,
                              hipStream_t stream) {
    const float* xyz = (const float*)d_in[0];
    const float* tables = (const float*)d_in[1];
    const int* resolutions = (const int*)d_in[2];
    float* out = (float*)d_out;

    int n = in_sizes[0] / 3;

    // choose K0 by available workspace: need (16-K0) * n * 8 bytes
    const size_t need2 = (size_t)(NLV - 2) * (size_t)n * sizeof(float2);
    const size_t need5 = (size_t)(NLV - 5) * (size_t)n * sizeof(float2);

    if (ws_size >= need2) {
        const int k0 = 2;
        int nbPerLevel = (n + 511) / 512;
        int grid1 = (NLV - k0) * nbPerLevel;
        hipLaunchKernelGGL(ngp_gather_levels, dim3(grid1), dim3(256), 0, stream,
                           xyz, tables, resolutions, (float2*)d_ws, n, nbPerLevel, k0);
        int grid2 = (n + 255) / 256;
        hipLaunchKernelGGL((ngp_finalize<2>), dim3(grid2), dim3(256), 0, stream,
                           xyz, tables, resolutions, (const float2*)d_ws, out, n);
    } else if (ws_size >= need5) {
        const int k0 = 5;
        int nbPerLevel = (n + 511) / 512;
        int grid1 = (NLV - k0) * nbPerLevel;
        hipLaunchKernelGGL(ngp_gather_levels, dim3(grid1), dim3(256), 0, stream,
                           xyz, tables, resolutions, (float2*)d_ws, n, nbPerLevel, k0);
        int grid2 = (n + 255) / 256;
        hipLaunchKernelGGL((ngp_finalize<5>), dim3(grid2), dim3(256), 0, stream,
                           xyz, tables, resolutions, (const float2*)d_ws, out, n);
    } else {
        int grid = (n + 255) / 256;
        hipLaunchKernelGGL(ngp_encode_kernel, dim3(grid), dim3(256), 0, stream,
                           xyz, tables, resolutions, out, n);
    }
}